// Round 14
// baseline (654.649 us; speedup 1.0000x reference)
//
#include <hip/hip_runtime.h>
#include <hip/hip_bf16.h>

// GraphSage: 3x SAGEConv(mean) + linear head.
// Precision: packed split-bf16 (uint32 = hi<<16|lo, val = f(hi)+f(lo)).
// Structure: SEPARATE aggregate and GEMM (r12 fusion starved the gather).
// Aggregate (r14): COLUMN-CHUNKED XCD-AFFINE gather. hp is only 25.6MB but
//   the r13 gather missed L2 42% (174MB past-L2 per dispatch): each 4MB
//   per-XCD L2 holds 1/6 of hp. Chunking cols into 8x16 (3.2MB, L2-resident)
//   and pinning chunk = blockIdx&7 (round-robin XCD heuristic) converts the
//   410MB gather demand into L2 hits. Quarter-wave per edge-slice, 4 edges
//   in flight x4 unroll; same fp32 summation -> same absmax.
// GEMM: weight-stationary MFMA, 2 ct/wave, 256 thr, GRID-STRIDE loop, all 16
//   A dwordx4 loads prefetched per tile (r13: GEMM was MLP-bound at 700GB/s).
//   NOTE: grid-stride loop is load-bearing — keeps the 128-VGPR B set live
//   (r6/r11 regressions: B demoted when loop removed or regs squeezed).
// CSR build: two-level MSD bucket sort — no random global scatter (r7-r9:
//   cross-XCD write amplification, 57-175us). Parallel basescan (r11).
// Head fused into layer-2 GEMM. packed[] aliases sbuf (disjoint lifetime).

constexpr int NN = 50000;
constexpr int NE = 800000;
constexpr int NTILE = NN / 16;          // 3125 exact
constexpr int EPB = 4096;
constexpr int NBLK = (NE + EPB - 1) / EPB;   // 196
constexpr int NBUCK = 196;
constexpr int BCAP = 6144;

using bf16x8 = __attribute__((ext_vector_type(8))) short;
using f32x4  = __attribute__((ext_vector_type(4))) float;

__device__ __forceinline__ unsigned short bf16_rne(float f) {
    unsigned u = __float_as_uint(f);
    unsigned r = (u + 0x7FFFu + ((u >> 16) & 1u)) >> 16;
    return (unsigned short)r;
}
__device__ __forceinline__ float bf16_f(unsigned short h) {
    return __uint_as_float(((unsigned)h) << 16);
}
__device__ __forceinline__ unsigned pack_split(float v) {
    unsigned short hi = bf16_rne(v);
    float r = v - bf16_f(hi);
    unsigned short lo = bf16_rne(r);
    return (((unsigned)hi) << 16) | (unsigned)lo;
}
__device__ __forceinline__ float unpack_f(unsigned p) {
    return __uint_as_float(p & 0xFFFF0000u) + __uint_as_float(p << 16);
}

// ---------------- CSR build (bucket sort) ----------------

__global__ __launch_bounds__(256) void k_hist(const int* __restrict__ ei,
                                              int* __restrict__ hist) {
    __shared__ int h[256];
    h[threadIdx.x] = 0;
    __syncthreads();
    int e0 = blockIdx.x * EPB;
    int e1 = e0 + EPB; if (e1 > NE) e1 = NE;
    for (int e = e0 + threadIdx.x; e < e1; e += 256)
        atomicAdd(&h[ei[NE + e] >> 8], 1);
    __syncthreads();
    hist[blockIdx.x * 256 + threadIdx.x] = h[threadIdx.x];
}

__global__ __launch_bounds__(256) void k_colscan(int* __restrict__ hist,
                                                 int* __restrict__ tot) {
    __shared__ int ws[4];
    int b = blockIdx.x;
    int t = threadIdx.x;
    int orig = (t < NBLK) ? hist[t * 256 + b] : 0;
    int v = orig;
    int lane = t & 63, wave = t >> 6;
    for (int o = 1; o < 64; o <<= 1) { int u = __shfl_up(v, o); if (lane >= o) v += u; }
    if (lane == 63) ws[wave] = v;
    __syncthreads();
    int off = 0;
    for (int w = 0; w < wave; ++w) off += ws[w];
    int st = v + off - orig;
    if (t < NBLK) hist[t * 256 + b] = st;
    if (t == 255) tot[b] = st + orig;
}

__global__ __launch_bounds__(256) void k_total(const int* __restrict__ tot,
                                               int* __restrict__ dbase) {
    __shared__ int ws[4];
    int t = threadIdx.x;
    int orig = tot[t];
    int v = orig;
    int lane = t & 63, wave = t >> 6;
    for (int o = 1; o < 64; o <<= 1) { int u = __shfl_up(v, o); if (lane >= o) v += u; }
    if (lane == 63) ws[wave] = v;
    __syncthreads();
    int off = 0;
    for (int w = 0; w < wave; ++w) off += ws[w];
    dbase[t] = v + off - orig;
    if (t == 255) dbase[256] = v + off;
}

__global__ __launch_bounds__(256) void k_addbase(int* __restrict__ hist,
                                                 const int* __restrict__ dbase) {
    hist[blockIdx.x * 256 + threadIdx.x] += dbase[threadIdx.x];
}

__global__ __launch_bounds__(256) void k_scatter1(const int* __restrict__ ei,
                                                  const int* __restrict__ hist,
                                                  unsigned* __restrict__ packed) {
    __shared__ int cur[256];
    cur[threadIdx.x] = hist[blockIdx.x * 256 + threadIdx.x];
    __syncthreads();
    int e0 = blockIdx.x * EPB;
    int e1 = e0 + EPB; if (e1 > NE) e1 = NE;
    for (int e = e0 + threadIdx.x; e < e1; e += 256) {
        int s = ei[e];
        int d = ei[NE + e];
        int pos = atomicAdd(&cur[d >> 8], 1);
        packed[pos] = ((unsigned)d << 16) | (unsigned)s;
    }
}

__global__ __launch_bounds__(256) void k_bucket_csr(const unsigned* __restrict__ packed,
        const int* __restrict__ dbase, unsigned short* __restrict__ perm,
        int* __restrict__ cnt, int* __restrict__ row_start) {
    __shared__ unsigned recs[BCAP];
    __shared__ unsigned short outs[BCAP];
    __shared__ int cntL[256];
    __shared__ int ws[4];
    int b = blockIdx.x;
    int lo = dbase[b];
    int m = dbase[b + 1] - lo;
    if (m > BCAP) m = BCAP;
    int t = threadIdx.x;
    cntL[t] = 0;
    __syncthreads();
    for (int i = t; i < m; i += 256) {
        unsigned r = packed[lo + i];
        recs[i] = r;
        atomicAdd(&cntL[(r >> 16) & 255], 1);
    }
    __syncthreads();
    int lane = t & 63, wave = t >> 6;
    int orig = cntL[t], v = orig;
    for (int o = 1; o < 64; o <<= 1) { int u = __shfl_up(v, o); if (lane >= o) v += u; }
    if (lane == 63) ws[wave] = v;
    __syncthreads();
    int off = 0;
    for (int w = 0; w < wave; ++w) off += ws[w];
    int st = v + off - orig;
    int node = b * 256 + t;
    if (node < NN) { cnt[node] = orig; row_start[node] = lo + st; }
    __syncthreads();
    cntL[t] = st;
    __syncthreads();
    for (int i = t; i < m; i += 256) {
        unsigned r = recs[i];
        int pos = atomicAdd(&cntL[(r >> 16) & 255], 1);
        outs[pos] = (unsigned short)(r & 0xFFFFu);
    }
    __syncthreads();
    for (int i = t; i < m; i += 256)
        perm[lo + i] = outs[i];
}

// ---------------- packing ----------------

__global__ void k_pack_x(const float* __restrict__ x, unsigned* __restrict__ xp) {
    int i = blockIdx.x * blockDim.x + threadIdx.x;
    constexpr int TOT = NN * 128 / 4;
    if (i < TOT) {
        float4 v = ((const float4*)x)[i];
        uint4 o;
        o.x = pack_split(v.x); o.y = pack_split(v.y);
        o.z = pack_split(v.z); o.w = pack_split(v.w);
        ((uint4*)xp)[i] = o;
    }
}

__global__ void k_pack_w(const float* __restrict__ Wl, const float* __restrict__ Wr,
                         unsigned short* __restrict__ whi, unsigned short* __restrict__ wlo) {
    int i = blockIdx.x * blockDim.x + threadIdx.x;
    if (i < 128 * 256) {
        int c = i >> 8;
        int k = i & 255;
        float v = (k < 128) ? Wl[c * 128 + k] : Wr[c * 128 + (k - 128)];
        unsigned short hi = bf16_rne(v);
        whi[i] = hi;
        wlo[i] = bf16_rne(v - bf16_f(hi));
    }
}

__global__ void k_init_out(float* __restrict__ out, const float* __restrict__ bf) {
    int i = blockIdx.x * blockDim.x + threadIdx.x;
    if (i < NN) out[i] = bf[0];
}

// ---------------- aggregate: column-chunked, XCD-affine ----------------
// chunk = blockIdx&7 owns cols [16c,16c+16) (3.2MB slice, L2-resident).
// wave = 1 node; quarter-wave (16 lanes) = one edge's 64B column slice;
// 4 edges in flight per gather group, x4 unroll (16 edges/iter).
__global__ __launch_bounds__(256) void k_aggregate_chunk(const unsigned* __restrict__ hp,
        const int* __restrict__ row_start, const int* __restrict__ cnt,
        const unsigned short* __restrict__ perm, unsigned* __restrict__ outp) {
    int wave = __builtin_amdgcn_readfirstlane(threadIdx.x >> 6);
    int lane = threadIdx.x & 63;
    int sub = lane >> 4;          // edge slot 0..3
    int col = lane & 15;          // col within chunk
    int chunk = blockIdx.x & 7;
    int node = (blockIdx.x >> 3) * 4 + wave;
    if (node >= NN) return;
    int deg = cnt[node];
    int start = row_start[node];
    const unsigned* base = hp + chunk * 16 + col;
    float a = 0.f;
    int j = 0;
    for (; j + 16 <= deg; j += 16) {
        int s0 = perm[start + j + sub];
        int s1 = perm[start + j + 4 + sub];
        int s2 = perm[start + j + 8 + sub];
        int s3 = perm[start + j + 12 + sub];
        unsigned q0 = base[(size_t)s0 * 128];
        unsigned q1 = base[(size_t)s1 * 128];
        unsigned q2 = base[(size_t)s2 * 128];
        unsigned q3 = base[(size_t)s3 * 128];
        a += (unpack_f(q0) + unpack_f(q1)) + (unpack_f(q2) + unpack_f(q3));
    }
    for (; j < deg; j += 4) {
        int e = j + sub;
        if (e < deg) {
            int s = perm[start + e];
            a += unpack_f(base[(size_t)s * 128]);
        }
    }
    a += __shfl_xor(a, 16);
    a += __shfl_xor(a, 32);
    if (sub == 0) {
        float inv = 1.0f / (float)(deg > 1 ? deg : 1);
        outp[(size_t)node * 128 + chunk * 16 + col] = pack_split(a * inv);
    }
}

// ---------------- weight-stationary MFMA GEMM (grid-stride) ----------------
// out[n][c] = relu( bias[c] + sum_k [A0|A1][n][k] W[c][k] )
// Wave w owns cols [32w,32w+32): B hi/lo = 128 VGPRs, live across tiles.
// Per tile: ALL 16 A dwordx4 loads issued up front (64 VGPRs) -> high MLP.
__global__ __launch_bounds__(256, 2) void k_gemm_ws(
        const unsigned* __restrict__ A0p, const unsigned* __restrict__ A1p,
        const unsigned short* __restrict__ Whi, const unsigned short* __restrict__ Wlo,
        const float* __restrict__ bias, unsigned* __restrict__ outp) {
    int wave = __builtin_amdgcn_readfirstlane(threadIdx.x >> 6);
    int lane = threadIdx.x & 63;
    int row = lane & 15;
    int kb = lane >> 4;
    int ct0 = wave * 2;

    bf16x8 bh[2][8], bl[2][8];
#pragma unroll
    for (int c = 0; c < 2; ++c)
#pragma unroll
        for (int kc = 0; kc < 8; ++kc) {
            size_t widx = (size_t)((ct0 + c) * 16 + row) * 256 + kc * 32 + kb * 8;
            bh[c][kc] = *(const bf16x8*)(Whi + widx);
            bl[c][kc] = *(const bf16x8*)(Wlo + widx);
        }
    float b0 = bias[ct0 * 16 + row];
    float b1 = bias[ct0 * 16 + 16 + row];

    for (int t = blockIdx.x; t < NTILE; t += gridDim.x) {
        int n0 = t * 16;
        const unsigned* a0 = A0p + (size_t)(n0 + row) * 128 + kb * 8;
        const unsigned* a1 = A1p + (size_t)(n0 + row) * 128 + kb * 8;
        uint4 aq[16];
#pragma unroll
        for (int kc = 0; kc < 4; ++kc) {
            aq[2 * kc + 0] = *(const uint4*)(a0 + kc * 32);
            aq[2 * kc + 1] = *(const uint4*)(a0 + kc * 32 + 4);
        }
#pragma unroll
        for (int kc = 0; kc < 4; ++kc) {
            aq[8 + 2 * kc + 0] = *(const uint4*)(a1 + kc * 32);
            aq[8 + 2 * kc + 1] = *(const uint4*)(a1 + kc * 32 + 4);
        }
        f32x4 acc0 = {0.f, 0.f, 0.f, 0.f};
        f32x4 acc1 = {0.f, 0.f, 0.f, 0.f};
#pragma unroll
        for (int kc = 0; kc < 8; ++kc) {
            uint4 q0 = aq[2 * kc];
            uint4 q1 = aq[2 * kc + 1];
            unsigned pk[8] = {q0.x, q0.y, q0.z, q0.w, q1.x, q1.y, q1.z, q1.w};
            bf16x8 ah, al;
#pragma unroll
            for (int j = 0; j < 8; ++j) {
                ah[j] = (short)(pk[j] >> 16);
                al[j] = (short)(pk[j] & 0xFFFFu);
            }
            acc0 = __builtin_amdgcn_mfma_f32_16x16x32_bf16(ah, bh[0][kc], acc0, 0, 0, 0);
            acc0 = __builtin_amdgcn_mfma_f32_16x16x32_bf16(al, bh[0][kc], acc0, 0, 0, 0);
            acc0 = __builtin_amdgcn_mfma_f32_16x16x32_bf16(ah, bl[0][kc], acc0, 0, 0, 0);
            acc1 = __builtin_amdgcn_mfma_f32_16x16x32_bf16(ah, bh[1][kc], acc1, 0, 0, 0);
            acc1 = __builtin_amdgcn_mfma_f32_16x16x32_bf16(al, bh[1][kc], acc1, 0, 0, 0);
            acc1 = __builtin_amdgcn_mfma_f32_16x16x32_bf16(ah, bl[1][kc], acc1, 0, 0, 0);
        }
        __syncthreads();   // all waves' reads of this tile's rows precede writes
        int cb0 = ct0 * 16 + row;
#pragma unroll
        for (int r = 0; r < 4; ++r) {
            int n = n0 + kb * 4 + r;         // D: col=lane&15, row=(lane>>4)*4+reg
            unsigned* orow = outp + (size_t)n * 128;
            orow[cb0]      = pack_split(fmaxf(acc0[r] + b0, 0.f));
            orow[cb0 + 16] = pack_split(fmaxf(acc1[r] + b1, 0.f));
        }
    }
}

// layer-2 variant: head fused — out[n] += sum_c relu(h3[n][c]) * Wf[c]
__global__ __launch_bounds__(256, 2) void k_gemm_head(
        const unsigned* __restrict__ A0p, const unsigned* __restrict__ A1p,
        const unsigned short* __restrict__ Whi, const unsigned short* __restrict__ Wlo,
        const float* __restrict__ bias, const float* __restrict__ Wf,
        float* __restrict__ out) {
    int wave = __builtin_amdgcn_readfirstlane(threadIdx.x >> 6);
    int lane = threadIdx.x & 63;
    int row = lane & 15;
    int kb = lane >> 4;
    int ct0 = wave * 2;

    bf16x8 bh[2][8], bl[2][8];
#pragma unroll
    for (int c = 0; c < 2; ++c)
#pragma unroll
        for (int kc = 0; kc < 8; ++kc) {
            size_t widx = (size_t)((ct0 + c) * 16 + row) * 256 + kc * 32 + kb * 8;
            bh[c][kc] = *(const bf16x8*)(Whi + widx);
            bl[c][kc] = *(const bf16x8*)(Wlo + widx);
        }
    float b0 = bias[ct0 * 16 + row];
    float b1 = bias[ct0 * 16 + 16 + row];
    float w0 = Wf[ct0 * 16 + row];
    float w1 = Wf[ct0 * 16 + 16 + row];

    for (int t = blockIdx.x; t < NTILE; t += gridDim.x) {
        int n0 = t * 16;
        const unsigned* a0 = A0p + (size_t)(n0 + row) * 128 + kb * 8;
        const unsigned* a1 = A1p + (size_t)(n0 + row) * 128 + kb * 8;
        uint4 aq[16];
#pragma unroll
        for (int kc = 0; kc < 4; ++kc) {
            aq[2 * kc + 0] = *(const uint4*)(a0 + kc * 32);
            aq[2 * kc + 1] = *(const uint4*)(a0 + kc * 32 + 4);
        }
#pragma unroll
        for (int kc = 0; kc < 4; ++kc) {
            aq[8 + 2 * kc + 0] = *(const uint4*)(a1 + kc * 32);
            aq[8 + 2 * kc + 1] = *(const uint4*)(a1 + kc * 32 + 4);
        }
        f32x4 acc0 = {0.f, 0.f, 0.f, 0.f};
        f32x4 acc1 = {0.f, 0.f, 0.f, 0.f};
#pragma unroll
        for (int kc = 0; kc < 8; ++kc) {
            uint4 q0 = aq[2 * kc];
            uint4 q1 = aq[2 * kc + 1];
            unsigned pk[8] = {q0.x, q0.y, q0.z, q0.w, q1.x, q1.y, q1.z, q1.w};
            bf16x8 ah, al;
#pragma unroll
            for (int j = 0; j < 8; ++j) {
                ah[j] = (short)(pk[j] >> 16);
                al[j] = (short)(pk[j] & 0xFFFFu);
            }
            acc0 = __builtin_amdgcn_mfma_f32_16x16x32_bf16(ah, bh[0][kc], acc0, 0, 0, 0);
            acc0 = __builtin_amdgcn_mfma_f32_16x16x32_bf16(al, bh[0][kc], acc0, 0, 0, 0);
            acc0 = __builtin_amdgcn_mfma_f32_16x16x32_bf16(ah, bl[0][kc], acc0, 0, 0, 0);
            acc1 = __builtin_amdgcn_mfma_f32_16x16x32_bf16(ah, bh[1][kc], acc1, 0, 0, 0);
            acc1 = __builtin_amdgcn_mfma_f32_16x16x32_bf16(al, bh[1][kc], acc1, 0, 0, 0);
            acc1 = __builtin_amdgcn_mfma_f32_16x16x32_bf16(ah, bl[1][kc], acc1, 0, 0, 0);
        }
        float part[4];
#pragma unroll
        for (int r = 0; r < 4; ++r)
            part[r] = fmaxf(acc0[r] + b0, 0.f) * w0 + fmaxf(acc1[r] + b1, 0.f) * w1;
#pragma unroll
        for (int o = 1; o < 16; o <<= 1) {
#pragma unroll
            for (int r = 0; r < 4; ++r) part[r] += __shfl_xor(part[r], o);
        }
        if (row == 0) {
#pragma unroll
            for (int r = 0; r < 4; ++r) atomicAdd(&out[n0 + kb * 4 + r], part[r]);
        }
    }
}

extern "C" void kernel_launch(void* const* d_in, const int* in_sizes, int n_in,
                              void* d_out, int out_size, void* d_ws, size_t ws_size,
                              hipStream_t stream) {
    const float* x   = (const float*)d_in[0];
    const int*   ei  = (const int*)d_in[1];
    const float* Wl0 = (const float*)d_in[2];
    const float* bl0 = (const float*)d_in[3];
    const float* Wr0 = (const float*)d_in[4];
    const float* Wl1 = (const float*)d_in[5];
    const float* bl1 = (const float*)d_in[6];
    const float* Wr1 = (const float*)d_in[7];
    const float* Wl2 = (const float*)d_in[8];
    const float* bl2 = (const float*)d_in[9];
    const float* Wr2 = (const float*)d_in[10];
    const float* Wf  = (const float*)d_in[11];
    const float* bf  = (const float*)d_in[12];
    float* out = (float*)d_out;

    char* p = (char*)d_ws;
    auto alloc = [&](size_t n) { void* r = (void*)p; p += (n + 255) & ~(size_t)255; return r; };
    int*            hist      = (int*)alloc((size_t)NBLK * 256 * 4);
    int*            tot       = (int*)alloc(256 * 4);
    int*            dbase     = (int*)alloc(257 * 4);
    int*            cnt       = (int*)alloc((size_t)NN * 4);
    int*            row_start = (int*)alloc((size_t)NN * 4);
    unsigned short* perm      = (unsigned short*)alloc((size_t)NE * 2);
    unsigned*       sbuf      = (unsigned*)alloc((size_t)NN * 128 * 4);
    unsigned*       hp        = (unsigned*)alloc((size_t)NN * 128 * 4);
    unsigned short* whi       = (unsigned short*)alloc((size_t)3 * 128 * 256 * 2);
    unsigned short* wlo       = (unsigned short*)alloc((size_t)3 * 128 * 256 * 2);
    unsigned*       packed    = sbuf;   // alias: consumed before first aggregate

    dim3 b256(256);
    // CSR build via bucket sort
    k_hist<<<dim3(NBLK), b256, 0, stream>>>(ei, hist);
    k_colscan<<<dim3(256), b256, 0, stream>>>(hist, tot);
    k_total<<<dim3(1), b256, 0, stream>>>(tot, dbase);
    k_addbase<<<dim3(NBLK), b256, 0, stream>>>(hist, dbase);
    k_scatter1<<<dim3(NBLK), b256, 0, stream>>>(ei, hist, packed);
    k_bucket_csr<<<dim3(NBUCK), b256, 0, stream>>>(packed, dbase, perm, cnt, row_start);

    // packing + out init
    k_pack_x<<<dim3((NN * 128 / 4 + 255) / 256), b256, 0, stream>>>(x, hp);
    k_pack_w<<<dim3(128), b256, 0, stream>>>(Wl0, Wr0, whi + 0 * 32768, wlo + 0 * 32768);
    k_pack_w<<<dim3(128), b256, 0, stream>>>(Wl1, Wr1, whi + 1 * 32768, wlo + 1 * 32768);
    k_pack_w<<<dim3(128), b256, 0, stream>>>(Wl2, Wr2, whi + 2 * 32768, wlo + 2 * 32768);
    k_init_out<<<dim3((NN + 255) / 256), b256, 0, stream>>>(out, bf);

    dim3 gAgg(8 * ((NN + 3) / 4));   // 8 col-chunks x (4 nodes/block)
    dim3 gGemm(512);                 // 2 blocks/CU; grid-stride over 3125 tiles

    // layer 0
    k_aggregate_chunk<<<gAgg, b256, 0, stream>>>(hp, row_start, cnt, perm, sbuf);
    k_gemm_ws<<<gGemm, b256, 0, stream>>>(sbuf, hp, whi + 0 * 32768, wlo + 0 * 32768, bl0, hp);
    // layer 1 (in place)
    k_aggregate_chunk<<<gAgg, b256, 0, stream>>>(hp, row_start, cnt, perm, sbuf);
    k_gemm_ws<<<gGemm, b256, 0, stream>>>(sbuf, hp, whi + 1 * 32768, wlo + 1 * 32768, bl1, hp);
    // layer 2 + fused head
    k_aggregate_chunk<<<gAgg, b256, 0, stream>>>(hp, row_start, cnt, perm, sbuf);
    k_gemm_head<<<gGemm, b256, 0, stream>>>(sbuf, hp, whi + 2 * 32768, wlo + 2 * 32768, bl2, Wf, out);
}

// Round 16
// 397.196 us; speedup vs baseline: 1.6482x; 1.6482x over previous
//
#include <hip/hip_runtime.h>
#include <hip/hip_bf16.h>

// GraphSage: 3x SAGEConv(mean) + linear head.  == r13 champion (399.5us) ==
// Precision: packed split-bf16 (uint32 = hi<<16|lo, val = f(hi)+f(lo)).
// Structure: SEPARATE aggregate and GEMM (r12 fusion starved the gather:
//   19% occ, 135us/layer).
// Aggregate: 1 node/wave, uint2 lanes, 16-deep unroll — at the beyond-L2
//   (L3-serve) throughput ceiling ~3.7TB/s for 174MB compulsory traffic.
//   FAILED alternatives: col-chunked blockIdx&7 (r14: XCD mapping false,
//   MLP collapsed, 144us); XCC_ID-pinned tickets (r15: s_getreg chunk not
//   block-uniform -> racy writes, replay-divergent + 1119us). XCD affinity
//   is NOT controllable from HIP — do not retry.
// GEMM: weight-stationary MFMA, 2 ct/wave, 256 thr, GRID-STRIDE loop, all 16
//   A dwordx4 loads prefetched per tile (fixed the 700GB/s MLP bound).
//   Grid-stride loop is load-bearing: keeps 128-VGPR B set live (r6/r11:
//   removing it or squeezing regs demotes B -> 65-75us).
// CSR build: two-level MSD bucket sort (r10; random atomic scatter is
//   cross-XCD write-amplification bound, 57-175us) + parallel basescan (r11).
// Head fused into layer-2 GEMM. packed[] aliases sbuf (disjoint lifetime).

constexpr int NN = 50000;
constexpr int NE = 800000;
constexpr int NTILE = NN / 16;          // 3125 exact
constexpr int EPB = 4096;
constexpr int NBLK = (NE + EPB - 1) / EPB;   // 196
constexpr int NBUCK = 196;
constexpr int BCAP = 6144;

using bf16x8 = __attribute__((ext_vector_type(8))) short;
using f32x4  = __attribute__((ext_vector_type(4))) float;

__device__ __forceinline__ unsigned short bf16_rne(float f) {
    unsigned u = __float_as_uint(f);
    unsigned r = (u + 0x7FFFu + ((u >> 16) & 1u)) >> 16;
    return (unsigned short)r;
}
__device__ __forceinline__ float bf16_f(unsigned short h) {
    return __uint_as_float(((unsigned)h) << 16);
}
__device__ __forceinline__ unsigned pack_split(float v) {
    unsigned short hi = bf16_rne(v);
    float r = v - bf16_f(hi);
    unsigned short lo = bf16_rne(r);
    return (((unsigned)hi) << 16) | (unsigned)lo;
}
__device__ __forceinline__ float unpack_f(unsigned p) {
    return __uint_as_float(p & 0xFFFF0000u) + __uint_as_float(p << 16);
}

// ---------------- CSR build (bucket sort) ----------------

__global__ __launch_bounds__(256) void k_hist(const int* __restrict__ ei,
                                              int* __restrict__ hist) {
    __shared__ int h[256];
    h[threadIdx.x] = 0;
    __syncthreads();
    int e0 = blockIdx.x * EPB;
    int e1 = e0 + EPB; if (e1 > NE) e1 = NE;
    for (int e = e0 + threadIdx.x; e < e1; e += 256)
        atomicAdd(&h[ei[NE + e] >> 8], 1);
    __syncthreads();
    hist[blockIdx.x * 256 + threadIdx.x] = h[threadIdx.x];
}

__global__ __launch_bounds__(256) void k_colscan(int* __restrict__ hist,
                                                 int* __restrict__ tot) {
    __shared__ int ws[4];
    int b = blockIdx.x;
    int t = threadIdx.x;
    int orig = (t < NBLK) ? hist[t * 256 + b] : 0;
    int v = orig;
    int lane = t & 63, wave = t >> 6;
    for (int o = 1; o < 64; o <<= 1) { int u = __shfl_up(v, o); if (lane >= o) v += u; }
    if (lane == 63) ws[wave] = v;
    __syncthreads();
    int off = 0;
    for (int w = 0; w < wave; ++w) off += ws[w];
    int st = v + off - orig;
    if (t < NBLK) hist[t * 256 + b] = st;
    if (t == 255) tot[b] = st + orig;
}

__global__ __launch_bounds__(256) void k_total(const int* __restrict__ tot,
                                               int* __restrict__ dbase) {
    __shared__ int ws[4];
    int t = threadIdx.x;
    int orig = tot[t];
    int v = orig;
    int lane = t & 63, wave = t >> 6;
    for (int o = 1; o < 64; o <<= 1) { int u = __shfl_up(v, o); if (lane >= o) v += u; }
    if (lane == 63) ws[wave] = v;
    __syncthreads();
    int off = 0;
    for (int w = 0; w < wave; ++w) off += ws[w];
    dbase[t] = v + off - orig;
    if (t == 255) dbase[256] = v + off;
}

__global__ __launch_bounds__(256) void k_addbase(int* __restrict__ hist,
                                                 const int* __restrict__ dbase) {
    hist[blockIdx.x * 256 + threadIdx.x] += dbase[threadIdx.x];
}

__global__ __launch_bounds__(256) void k_scatter1(const int* __restrict__ ei,
                                                  const int* __restrict__ hist,
                                                  unsigned* __restrict__ packed) {
    __shared__ int cur[256];
    cur[threadIdx.x] = hist[blockIdx.x * 256 + threadIdx.x];
    __syncthreads();
    int e0 = blockIdx.x * EPB;
    int e1 = e0 + EPB; if (e1 > NE) e1 = NE;
    for (int e = e0 + threadIdx.x; e < e1; e += 256) {
        int s = ei[e];
        int d = ei[NE + e];
        int pos = atomicAdd(&cur[d >> 8], 1);
        packed[pos] = ((unsigned)d << 16) | (unsigned)s;
    }
}

__global__ __launch_bounds__(256) void k_bucket_csr(const unsigned* __restrict__ packed,
        const int* __restrict__ dbase, unsigned short* __restrict__ perm,
        int* __restrict__ cnt, int* __restrict__ row_start) {
    __shared__ unsigned recs[BCAP];
    __shared__ unsigned short outs[BCAP];
    __shared__ int cntL[256];
    __shared__ int ws[4];
    int b = blockIdx.x;
    int lo = dbase[b];
    int m = dbase[b + 1] - lo;
    if (m > BCAP) m = BCAP;
    int t = threadIdx.x;
    cntL[t] = 0;
    __syncthreads();
    for (int i = t; i < m; i += 256) {
        unsigned r = packed[lo + i];
        recs[i] = r;
        atomicAdd(&cntL[(r >> 16) & 255], 1);
    }
    __syncthreads();
    int lane = t & 63, wave = t >> 6;
    int orig = cntL[t], v = orig;
    for (int o = 1; o < 64; o <<= 1) { int u = __shfl_up(v, o); if (lane >= o) v += u; }
    if (lane == 63) ws[wave] = v;
    __syncthreads();
    int off = 0;
    for (int w = 0; w < wave; ++w) off += ws[w];
    int st = v + off - orig;
    int node = b * 256 + t;
    if (node < NN) { cnt[node] = orig; row_start[node] = lo + st; }
    __syncthreads();
    cntL[t] = st;
    __syncthreads();
    for (int i = t; i < m; i += 256) {
        unsigned r = recs[i];
        int pos = atomicAdd(&cntL[(r >> 16) & 255], 1);
        outs[pos] = (unsigned short)(r & 0xFFFFu);
    }
    __syncthreads();
    for (int i = t; i < m; i += 256)
        perm[lo + i] = outs[i];
}

// ---------------- packing ----------------

__global__ void k_pack_x(const float* __restrict__ x, unsigned* __restrict__ xp) {
    int i = blockIdx.x * blockDim.x + threadIdx.x;
    constexpr int TOT = NN * 128 / 4;
    if (i < TOT) {
        float4 v = ((const float4*)x)[i];
        uint4 o;
        o.x = pack_split(v.x); o.y = pack_split(v.y);
        o.z = pack_split(v.z); o.w = pack_split(v.w);
        ((uint4*)xp)[i] = o;
    }
}

__global__ void k_pack_w(const float* __restrict__ Wl, const float* __restrict__ Wr,
                         unsigned short* __restrict__ whi, unsigned short* __restrict__ wlo) {
    int i = blockIdx.x * blockDim.x + threadIdx.x;
    if (i < 128 * 256) {
        int c = i >> 8;
        int k = i & 255;
        float v = (k < 128) ? Wl[c * 128 + k] : Wr[c * 128 + (k - 128)];
        unsigned short hi = bf16_rne(v);
        whi[i] = hi;
        wlo[i] = bf16_rne(v - bf16_f(hi));
    }
}

__global__ void k_init_out(float* __restrict__ out, const float* __restrict__ bf) {
    int i = blockIdx.x * blockDim.x + threadIdx.x;
    if (i < NN) out[i] = bf[0];
}

// ---------------- aggregate (mean over CSR neighbors) ----------------
// one wave per node; lane l holds cols [2l, 2l+1] (packed uint2).
__global__ __launch_bounds__(256) void k_aggregate(const unsigned* __restrict__ hp,
        const int* __restrict__ row_start, const int* __restrict__ cnt,
        const unsigned short* __restrict__ perm, unsigned* __restrict__ outp) {
    int wave = __builtin_amdgcn_readfirstlane(threadIdx.x >> 6);
    int lane = threadIdx.x & 63;
    int node = blockIdx.x * 4 + wave;
    if (node >= NN) return;
    int deg = cnt[node];
    int start = row_start[node];
    const uint2* base = (const uint2*)hp;    // row stride = 64 uint2
    float ax = 0.f, ay = 0.f;
    int j = 0;
    for (; j + 16 <= deg; j += 16) {
        int s[16];
#pragma unroll
        for (int u = 0; u < 16; ++u) s[u] = perm[start + j + u];
        uint2 q[16];
#pragma unroll
        for (int u = 0; u < 16; ++u) q[u] = base[(size_t)s[u] * 64 + lane];
#pragma unroll
        for (int u = 0; u < 16; ++u) { ax += unpack_f(q[u].x); ay += unpack_f(q[u].y); }
    }
    for (; j + 4 <= deg; j += 4) {
        int s[4];
#pragma unroll
        for (int u = 0; u < 4; ++u) s[u] = perm[start + j + u];
        uint2 q[4];
#pragma unroll
        for (int u = 0; u < 4; ++u) q[u] = base[(size_t)s[u] * 64 + lane];
#pragma unroll
        for (int u = 0; u < 4; ++u) { ax += unpack_f(q[u].x); ay += unpack_f(q[u].y); }
    }
    for (; j < deg; ++j) {
        int s = perm[start + j];
        uint2 q = base[(size_t)s * 64 + lane];
        ax += unpack_f(q.x);
        ay += unpack_f(q.y);
    }
    float inv = 1.0f / (float)(deg > 1 ? deg : 1);
    uint2 o;
    o.x = pack_split(ax * inv);
    o.y = pack_split(ay * inv);
    ((uint2*)(outp + (size_t)node * 128))[lane] = o;
}

// ---------------- weight-stationary MFMA GEMM (grid-stride) ----------------
// out[n][c] = relu( bias[c] + sum_k [A0|A1][n][k] W[c][k] )
// Wave w owns cols [32w,32w+32): B hi/lo = 128 VGPRs, live across tiles.
// Per tile: ALL 16 A dwordx4 loads issued up front (64 VGPRs) -> high MLP.
__global__ __launch_bounds__(256, 2) void k_gemm_ws(
        const unsigned* __restrict__ A0p, const unsigned* __restrict__ A1p,
        const unsigned short* __restrict__ Whi, const unsigned short* __restrict__ Wlo,
        const float* __restrict__ bias, unsigned* __restrict__ outp) {
    int wave = __builtin_amdgcn_readfirstlane(threadIdx.x >> 6);
    int lane = threadIdx.x & 63;
    int row = lane & 15;
    int kb = lane >> 4;
    int ct0 = wave * 2;

    bf16x8 bh[2][8], bl[2][8];
#pragma unroll
    for (int c = 0; c < 2; ++c)
#pragma unroll
        for (int kc = 0; kc < 8; ++kc) {
            size_t widx = (size_t)((ct0 + c) * 16 + row) * 256 + kc * 32 + kb * 8;
            bh[c][kc] = *(const bf16x8*)(Whi + widx);
            bl[c][kc] = *(const bf16x8*)(Wlo + widx);
        }
    float b0 = bias[ct0 * 16 + row];
    float b1 = bias[ct0 * 16 + 16 + row];

    for (int t = blockIdx.x; t < NTILE; t += gridDim.x) {
        int n0 = t * 16;
        const unsigned* a0 = A0p + (size_t)(n0 + row) * 128 + kb * 8;
        const unsigned* a1 = A1p + (size_t)(n0 + row) * 128 + kb * 8;
        uint4 aq[16];
#pragma unroll
        for (int kc = 0; kc < 4; ++kc) {
            aq[2 * kc + 0] = *(const uint4*)(a0 + kc * 32);
            aq[2 * kc + 1] = *(const uint4*)(a0 + kc * 32 + 4);
        }
#pragma unroll
        for (int kc = 0; kc < 4; ++kc) {
            aq[8 + 2 * kc + 0] = *(const uint4*)(a1 + kc * 32);
            aq[8 + 2 * kc + 1] = *(const uint4*)(a1 + kc * 32 + 4);
        }
        f32x4 acc0 = {0.f, 0.f, 0.f, 0.f};
        f32x4 acc1 = {0.f, 0.f, 0.f, 0.f};
#pragma unroll
        for (int kc = 0; kc < 8; ++kc) {
            uint4 q0 = aq[2 * kc];
            uint4 q1 = aq[2 * kc + 1];
            unsigned pk[8] = {q0.x, q0.y, q0.z, q0.w, q1.x, q1.y, q1.z, q1.w};
            bf16x8 ah, al;
#pragma unroll
            for (int j = 0; j < 8; ++j) {
                ah[j] = (short)(pk[j] >> 16);
                al[j] = (short)(pk[j] & 0xFFFFu);
            }
            acc0 = __builtin_amdgcn_mfma_f32_16x16x32_bf16(ah, bh[0][kc], acc0, 0, 0, 0);
            acc0 = __builtin_amdgcn_mfma_f32_16x16x32_bf16(al, bh[0][kc], acc0, 0, 0, 0);
            acc0 = __builtin_amdgcn_mfma_f32_16x16x32_bf16(ah, bl[0][kc], acc0, 0, 0, 0);
            acc1 = __builtin_amdgcn_mfma_f32_16x16x32_bf16(ah, bh[1][kc], acc1, 0, 0, 0);
            acc1 = __builtin_amdgcn_mfma_f32_16x16x32_bf16(al, bh[1][kc], acc1, 0, 0, 0);
            acc1 = __builtin_amdgcn_mfma_f32_16x16x32_bf16(ah, bl[1][kc], acc1, 0, 0, 0);
        }
        __syncthreads();   // all waves' reads of this tile's rows precede writes
        int cb0 = ct0 * 16 + row;
#pragma unroll
        for (int r = 0; r < 4; ++r) {
            int n = n0 + kb * 4 + r;         // D: col=lane&15, row=(lane>>4)*4+reg
            unsigned* orow = outp + (size_t)n * 128;
            orow[cb0]      = pack_split(fmaxf(acc0[r] + b0, 0.f));
            orow[cb0 + 16] = pack_split(fmaxf(acc1[r] + b1, 0.f));
        }
    }
}

// layer-2 variant: head fused — out[n] += sum_c relu(h3[n][c]) * Wf[c]
__global__ __launch_bounds__(256, 2) void k_gemm_head(
        const unsigned* __restrict__ A0p, const unsigned* __restrict__ A1p,
        const unsigned short* __restrict__ Whi, const unsigned short* __restrict__ Wlo,
        const float* __restrict__ bias, const float* __restrict__ Wf,
        float* __restrict__ out) {
    int wave = __builtin_amdgcn_readfirstlane(threadIdx.x >> 6);
    int lane = threadIdx.x & 63;
    int row = lane & 15;
    int kb = lane >> 4;
    int ct0 = wave * 2;

    bf16x8 bh[2][8], bl[2][8];
#pragma unroll
    for (int c = 0; c < 2; ++c)
#pragma unroll
        for (int kc = 0; kc < 8; ++kc) {
            size_t widx = (size_t)((ct0 + c) * 16 + row) * 256 + kc * 32 + kb * 8;
            bh[c][kc] = *(const bf16x8*)(Whi + widx);
            bl[c][kc] = *(const bf16x8*)(Wlo + widx);
        }
    float b0 = bias[ct0 * 16 + row];
    float b1 = bias[ct0 * 16 + 16 + row];
    float w0 = Wf[ct0 * 16 + row];
    float w1 = Wf[ct0 * 16 + 16 + row];

    for (int t = blockIdx.x; t < NTILE; t += gridDim.x) {
        int n0 = t * 16;
        const unsigned* a0 = A0p + (size_t)(n0 + row) * 128 + kb * 8;
        const unsigned* a1 = A1p + (size_t)(n0 + row) * 128 + kb * 8;
        uint4 aq[16];
#pragma unroll
        for (int kc = 0; kc < 4; ++kc) {
            aq[2 * kc + 0] = *(const uint4*)(a0 + kc * 32);
            aq[2 * kc + 1] = *(const uint4*)(a0 + kc * 32 + 4);
        }
#pragma unroll
        for (int kc = 0; kc < 4; ++kc) {
            aq[8 + 2 * kc + 0] = *(const uint4*)(a1 + kc * 32);
            aq[8 + 2 * kc + 1] = *(const uint4*)(a1 + kc * 32 + 4);
        }
        f32x4 acc0 = {0.f, 0.f, 0.f, 0.f};
        f32x4 acc1 = {0.f, 0.f, 0.f, 0.f};
#pragma unroll
        for (int kc = 0; kc < 8; ++kc) {
            uint4 q0 = aq[2 * kc];
            uint4 q1 = aq[2 * kc + 1];
            unsigned pk[8] = {q0.x, q0.y, q0.z, q0.w, q1.x, q1.y, q1.z, q1.w};
            bf16x8 ah, al;
#pragma unroll
            for (int j = 0; j < 8; ++j) {
                ah[j] = (short)(pk[j] >> 16);
                al[j] = (short)(pk[j] & 0xFFFFu);
            }
            acc0 = __builtin_amdgcn_mfma_f32_16x16x32_bf16(ah, bh[0][kc], acc0, 0, 0, 0);
            acc0 = __builtin_amdgcn_mfma_f32_16x16x32_bf16(al, bh[0][kc], acc0, 0, 0, 0);
            acc0 = __builtin_amdgcn_mfma_f32_16x16x32_bf16(ah, bl[0][kc], acc0, 0, 0, 0);
            acc1 = __builtin_amdgcn_mfma_f32_16x16x32_bf16(ah, bh[1][kc], acc1, 0, 0, 0);
            acc1 = __builtin_amdgcn_mfma_f32_16x16x32_bf16(al, bh[1][kc], acc1, 0, 0, 0);
            acc1 = __builtin_amdgcn_mfma_f32_16x16x32_bf16(ah, bl[1][kc], acc1, 0, 0, 0);
        }
        float part[4];
#pragma unroll
        for (int r = 0; r < 4; ++r)
            part[r] = fmaxf(acc0[r] + b0, 0.f) * w0 + fmaxf(acc1[r] + b1, 0.f) * w1;
#pragma unroll
        for (int o = 1; o < 16; o <<= 1) {
#pragma unroll
            for (int r = 0; r < 4; ++r) part[r] += __shfl_xor(part[r], o);
        }
        if (row == 0) {
#pragma unroll
            for (int r = 0; r < 4; ++r) atomicAdd(&out[n0 + kb * 4 + r], part[r]);
        }
    }
}

extern "C" void kernel_launch(void* const* d_in, const int* in_sizes, int n_in,
                              void* d_out, int out_size, void* d_ws, size_t ws_size,
                              hipStream_t stream) {
    const float* x   = (const float*)d_in[0];
    const int*   ei  = (const int*)d_in[1];
    const float* Wl0 = (const float*)d_in[2];
    const float* bl0 = (const float*)d_in[3];
    const float* Wr0 = (const float*)d_in[4];
    const float* Wl1 = (const float*)d_in[5];
    const float* bl1 = (const float*)d_in[6];
    const float* Wr1 = (const float*)d_in[7];
    const float* Wl2 = (const float*)d_in[8];
    const float* bl2 = (const float*)d_in[9];
    const float* Wr2 = (const float*)d_in[10];
    const float* Wf  = (const float*)d_in[11];
    const float* bf  = (const float*)d_in[12];
    float* out = (float*)d_out;

    char* p = (char*)d_ws;
    auto alloc = [&](size_t n) { void* r = (void*)p; p += (n + 255) & ~(size_t)255; return r; };
    int*            hist      = (int*)alloc((size_t)NBLK * 256 * 4);
    int*            tot       = (int*)alloc(256 * 4);
    int*            dbase     = (int*)alloc(257 * 4);
    int*            cnt       = (int*)alloc((size_t)NN * 4);
    int*            row_start = (int*)alloc((size_t)NN * 4);
    unsigned short* perm      = (unsigned short*)alloc((size_t)NE * 2);
    unsigned*       sbuf      = (unsigned*)alloc((size_t)NN * 128 * 4);
    unsigned*       hp        = (unsigned*)alloc((size_t)NN * 128 * 4);
    unsigned short* whi       = (unsigned short*)alloc((size_t)3 * 128 * 256 * 2);
    unsigned short* wlo       = (unsigned short*)alloc((size_t)3 * 128 * 256 * 2);
    unsigned*       packed    = sbuf;   // alias: consumed before first aggregate

    dim3 b256(256);
    // CSR build via bucket sort
    k_hist<<<dim3(NBLK), b256, 0, stream>>>(ei, hist);
    k_colscan<<<dim3(256), b256, 0, stream>>>(hist, tot);
    k_total<<<dim3(1), b256, 0, stream>>>(tot, dbase);
    k_addbase<<<dim3(NBLK), b256, 0, stream>>>(hist, dbase);
    k_scatter1<<<dim3(NBLK), b256, 0, stream>>>(ei, hist, packed);
    k_bucket_csr<<<dim3(NBUCK), b256, 0, stream>>>(packed, dbase, perm, cnt, row_start);

    // packing + out init
    k_pack_x<<<dim3((NN * 128 / 4 + 255) / 256), b256, 0, stream>>>(x, hp);
    k_pack_w<<<dim3(128), b256, 0, stream>>>(Wl0, Wr0, whi + 0 * 32768, wlo + 0 * 32768);
    k_pack_w<<<dim3(128), b256, 0, stream>>>(Wl1, Wr1, whi + 1 * 32768, wlo + 1 * 32768);
    k_pack_w<<<dim3(128), b256, 0, stream>>>(Wl2, Wr2, whi + 2 * 32768, wlo + 2 * 32768);
    k_init_out<<<dim3((NN + 255) / 256), b256, 0, stream>>>(out, bf);

    dim3 gAgg((NN + 3) / 4);    // 1 node/wave, 4 per block
    dim3 gGemm(512);            // 2 blocks/CU; grid-stride over 3125 tiles

    // layer 0
    k_aggregate<<<gAgg, b256, 0, stream>>>(hp, row_start, cnt, perm, sbuf);
    k_gemm_ws<<<gGemm, b256, 0, stream>>>(sbuf, hp, whi + 0 * 32768, wlo + 0 * 32768, bl0, hp);
    // layer 1 (in place)
    k_aggregate<<<gAgg, b256, 0, stream>>>(hp, row_start, cnt, perm, sbuf);
    k_gemm_ws<<<gGemm, b256, 0, stream>>>(sbuf, hp, whi + 1 * 32768, wlo + 1 * 32768, bl1, hp);
    // layer 2 + fused head
    k_aggregate<<<gAgg, b256, 0, stream>>>(hp, row_start, cnt, perm, sbuf);
    k_gemm_head<<<gGemm, b256, 0, stream>>>(sbuf, hp, whi + 2 * 32768, wlo + 2 * 32768, bl2, Wf, out);
}

// Round 17
// 336.598 us; speedup vs baseline: 1.9449x; 1.1800x over previous
//
#include <hip/hip_runtime.h>
#include <hip/hip_bf16.h>

// GraphSage: 3x SAGEConv(mean) + linear head.
// r17: PLANAR split-bf16 feature storage (hi-plane ushort[N][128] + lo-plane,
//   same 25.6MB total as the old packed u32). Aggregate gathers ONLY the hi
//   plane (256B/row = half the r13 bytes; mean inputs need only bf16 — extra
//   error ~2^-9 averaged over ~16 neighbors ≈ 1e-3 final, thr 3.85e-3).
//   Mean re-split exactly into sbuf planes; GEMM keeps full split precision
//   and now loads ah/al DIRECTLY from planes (repack VALU deleted).
// Structure: SEPARATE aggregate and GEMM (r12 fusion starved the gather).
// Aggregate: 1 node/wave, u32 lanes (2 cols), 16-deep unroll (16 rows in
//   flight — MLP preserved). XCD affinity is NOT controllable from HIP
//   (r14 blockIdx&7 false; r15 s_getreg racy) — do not retry.
// GEMM: weight-stationary MFMA, 2 ct/wave, 256 thr, GRID-STRIDE loop, all 16
//   A dwordx4 loads prefetched per tile. Grid-stride loop is load-bearing:
//   keeps 128-VGPR B set live (r6/r11: removing it demotes B -> 65-75us).
// CSR build: two-level MSD bucket sort (r10) + parallel basescan (r11).
// Head fused into layer-2 GEMM. packed[] aliases sbuf-hi (disjoint lifetime).

constexpr int NN = 50000;
constexpr int NE = 800000;
constexpr int NTILE = NN / 16;          // 3125 exact
constexpr int EPB = 4096;
constexpr int NBLK = (NE + EPB - 1) / EPB;   // 196
constexpr int NBUCK = 196;
constexpr int BCAP = 6144;

using bf16x8 = __attribute__((ext_vector_type(8))) short;
using f32x4  = __attribute__((ext_vector_type(4))) float;

__device__ __forceinline__ unsigned short bf16_rne(float f) {
    unsigned u = __float_as_uint(f);
    unsigned r = (u + 0x7FFFu + ((u >> 16) & 1u)) >> 16;
    return (unsigned short)r;
}
__device__ __forceinline__ float bf16_f(unsigned short h) {
    return __uint_as_float(((unsigned)h) << 16);
}
__device__ __forceinline__ unsigned pack_split(float v) {
    unsigned short hi = bf16_rne(v);
    float r = v - bf16_f(hi);
    unsigned short lo = bf16_rne(r);
    return (((unsigned)hi) << 16) | (unsigned)lo;
}

// ---------------- CSR build (bucket sort) ----------------

__global__ __launch_bounds__(256) void k_hist(const int* __restrict__ ei,
                                              int* __restrict__ hist) {
    __shared__ int h[256];
    h[threadIdx.x] = 0;
    __syncthreads();
    int e0 = blockIdx.x * EPB;
    int e1 = e0 + EPB; if (e1 > NE) e1 = NE;
    for (int e = e0 + threadIdx.x; e < e1; e += 256)
        atomicAdd(&h[ei[NE + e] >> 8], 1);
    __syncthreads();
    hist[blockIdx.x * 256 + threadIdx.x] = h[threadIdx.x];
}

__global__ __launch_bounds__(256) void k_colscan(int* __restrict__ hist,
                                                 int* __restrict__ tot) {
    __shared__ int ws[4];
    int b = blockIdx.x;
    int t = threadIdx.x;
    int orig = (t < NBLK) ? hist[t * 256 + b] : 0;
    int v = orig;
    int lane = t & 63, wave = t >> 6;
    for (int o = 1; o < 64; o <<= 1) { int u = __shfl_up(v, o); if (lane >= o) v += u; }
    if (lane == 63) ws[wave] = v;
    __syncthreads();
    int off = 0;
    for (int w = 0; w < wave; ++w) off += ws[w];
    int st = v + off - orig;
    if (t < NBLK) hist[t * 256 + b] = st;
    if (t == 255) tot[b] = st + orig;
}

__global__ __launch_bounds__(256) void k_total(const int* __restrict__ tot,
                                               int* __restrict__ dbase) {
    __shared__ int ws[4];
    int t = threadIdx.x;
    int orig = tot[t];
    int v = orig;
    int lane = t & 63, wave = t >> 6;
    for (int o = 1; o < 64; o <<= 1) { int u = __shfl_up(v, o); if (lane >= o) v += u; }
    if (lane == 63) ws[wave] = v;
    __syncthreads();
    int off = 0;
    for (int w = 0; w < wave; ++w) off += ws[w];
    dbase[t] = v + off - orig;
    if (t == 255) dbase[256] = v + off;
}

__global__ __launch_bounds__(256) void k_addbase(int* __restrict__ hist,
                                                 const int* __restrict__ dbase) {
    hist[blockIdx.x * 256 + threadIdx.x] += dbase[threadIdx.x];
}

__global__ __launch_bounds__(256) void k_scatter1(const int* __restrict__ ei,
                                                  const int* __restrict__ hist,
                                                  unsigned* __restrict__ packed) {
    __shared__ int cur[256];
    cur[threadIdx.x] = hist[blockIdx.x * 256 + threadIdx.x];
    __syncthreads();
    int e0 = blockIdx.x * EPB;
    int e1 = e0 + EPB; if (e1 > NE) e1 = NE;
    for (int e = e0 + threadIdx.x; e < e1; e += 256) {
        int s = ei[e];
        int d = ei[NE + e];
        int pos = atomicAdd(&cur[d >> 8], 1);
        packed[pos] = ((unsigned)d << 16) | (unsigned)s;
    }
}

__global__ __launch_bounds__(256) void k_bucket_csr(const unsigned* __restrict__ packed,
        const int* __restrict__ dbase, unsigned short* __restrict__ perm,
        int* __restrict__ cnt, int* __restrict__ row_start) {
    __shared__ unsigned recs[BCAP];
    __shared__ unsigned short outs[BCAP];
    __shared__ int cntL[256];
    __shared__ int ws[4];
    int b = blockIdx.x;
    int lo = dbase[b];
    int m = dbase[b + 1] - lo;
    if (m > BCAP) m = BCAP;
    int t = threadIdx.x;
    cntL[t] = 0;
    __syncthreads();
    for (int i = t; i < m; i += 256) {
        unsigned r = packed[lo + i];
        recs[i] = r;
        atomicAdd(&cntL[(r >> 16) & 255], 1);
    }
    __syncthreads();
    int lane = t & 63, wave = t >> 6;
    int orig = cntL[t], v = orig;
    for (int o = 1; o < 64; o <<= 1) { int u = __shfl_up(v, o); if (lane >= o) v += u; }
    if (lane == 63) ws[wave] = v;
    __syncthreads();
    int off = 0;
    for (int w = 0; w < wave; ++w) off += ws[w];
    int st = v + off - orig;
    int node = b * 256 + t;
    if (node < NN) { cnt[node] = orig; row_start[node] = lo + st; }
    __syncthreads();
    cntL[t] = st;
    __syncthreads();
    for (int i = t; i < m; i += 256) {
        unsigned r = recs[i];
        int pos = atomicAdd(&cntL[(r >> 16) & 255], 1);
        outs[pos] = (unsigned short)(r & 0xFFFFu);
    }
    __syncthreads();
    for (int i = t; i < m; i += 256)
        perm[lo + i] = outs[i];
}

// ---------------- packing ----------------

// x fp32 -> planar hi/lo bf16
__global__ void k_pack_x(const float* __restrict__ x,
                         unsigned short* __restrict__ hhi,
                         unsigned short* __restrict__ hlo) {
    int i = blockIdx.x * blockDim.x + threadIdx.x;
    constexpr int TOT = NN * 128 / 4;
    if (i < TOT) {
        float4 v = ((const float4*)x)[i];
        unsigned p0 = pack_split(v.x), p1 = pack_split(v.y);
        unsigned p2 = pack_split(v.z), p3 = pack_split(v.w);
        uint2 hi, lo;
        hi.x = (p0 >> 16) | (p1 & 0xFFFF0000u);
        hi.y = (p2 >> 16) | (p3 & 0xFFFF0000u);
        lo.x = (p0 & 0xFFFFu) | (p1 << 16);
        lo.y = (p2 & 0xFFFFu) | (p3 << 16);
        ((uint2*)hhi)[i] = hi;
        ((uint2*)hlo)[i] = lo;
    }
}

__global__ void k_pack_w(const float* __restrict__ Wl, const float* __restrict__ Wr,
                         unsigned short* __restrict__ whi, unsigned short* __restrict__ wlo) {
    int i = blockIdx.x * blockDim.x + threadIdx.x;
    if (i < 128 * 256) {
        int c = i >> 8;
        int k = i & 255;
        float v = (k < 128) ? Wl[c * 128 + k] : Wr[c * 128 + (k - 128)];
        unsigned short hi = bf16_rne(v);
        whi[i] = hi;
        wlo[i] = bf16_rne(v - bf16_f(hi));
    }
}

__global__ void k_init_out(float* __restrict__ out, const float* __restrict__ bf) {
    int i = blockIdx.x * blockDim.x + threadIdx.x;
    if (i < NN) out[i] = bf[0];
}

// ---------------- aggregate (mean over CSR neighbors, hi-plane only) -------
// one wave per node; lane l reads u32 = cols {2l (low ushort), 2l+1 (high)}.
// 16-deep unroll -> 16 x 256B rows in flight.
__global__ __launch_bounds__(256) void k_aggregate(const unsigned short* __restrict__ hhi,
        const int* __restrict__ row_start, const int* __restrict__ cnt,
        const unsigned short* __restrict__ perm,
        unsigned short* __restrict__ shi, unsigned short* __restrict__ slo) {
    int wave = __builtin_amdgcn_readfirstlane(threadIdx.x >> 6);
    int lane = threadIdx.x & 63;
    int node = blockIdx.x * 4 + wave;
    if (node >= NN) return;
    int deg = cnt[node];
    int start = row_start[node];
    const unsigned* base = (const unsigned*)hhi;   // row stride = 64 u32
    float ax = 0.f, ay = 0.f;
    int j = 0;
    for (; j + 16 <= deg; j += 16) {
        int s[16];
#pragma unroll
        for (int u = 0; u < 16; ++u) s[u] = perm[start + j + u];
        unsigned q[16];
#pragma unroll
        for (int u = 0; u < 16; ++u) q[u] = base[(size_t)s[u] * 64 + lane];
#pragma unroll
        for (int u = 0; u < 16; ++u) {
            ax += __uint_as_float(q[u] << 16);
            ay += __uint_as_float(q[u] & 0xFFFF0000u);
        }
    }
    for (; j + 4 <= deg; j += 4) {
        int s[4];
#pragma unroll
        for (int u = 0; u < 4; ++u) s[u] = perm[start + j + u];
        unsigned q[4];
#pragma unroll
        for (int u = 0; u < 4; ++u) q[u] = base[(size_t)s[u] * 64 + lane];
#pragma unroll
        for (int u = 0; u < 4; ++u) {
            ax += __uint_as_float(q[u] << 16);
            ay += __uint_as_float(q[u] & 0xFFFF0000u);
        }
    }
    for (; j < deg; ++j) {
        int s = perm[start + j];
        unsigned q = base[(size_t)s * 64 + lane];
        ax += __uint_as_float(q << 16);
        ay += __uint_as_float(q & 0xFFFF0000u);
    }
    float inv = 1.0f / (float)(deg > 1 ? deg : 1);
    unsigned p0 = pack_split(ax * inv);   // col 2l
    unsigned p1 = pack_split(ay * inv);   // col 2l+1
    ((unsigned*)shi)[(size_t)node * 64 + lane] = (p0 >> 16) | (p1 & 0xFFFF0000u);
    ((unsigned*)slo)[(size_t)node * 64 + lane] = (p0 & 0xFFFFu) | (p1 << 16);
}

// ---------------- weight-stationary MFMA GEMM (grid-stride) ----------------
// out[n][c] = relu( bias[c] + sum_k [A0|A1][n][k] W[c][k] )
// A operands load DIRECTLY from planes as bf16x8 (no repack). 16 x 16B A
// loads prefetched per tile (64 VGPRs) -> high MLP. B = 128 VGPRs, live
// across the grid-stride loop (load-bearing). In-place safe via barrier.
__global__ __launch_bounds__(256, 2) void k_gemm_ws(
        const unsigned short* __restrict__ Ahi0, const unsigned short* __restrict__ Alo0,
        const unsigned short* __restrict__ Ahi1, const unsigned short* __restrict__ Alo1,
        const unsigned short* __restrict__ Whi, const unsigned short* __restrict__ Wlo,
        const float* __restrict__ bias,
        unsigned short* __restrict__ Ohi, unsigned short* __restrict__ Olo) {
    int wave = __builtin_amdgcn_readfirstlane(threadIdx.x >> 6);
    int lane = threadIdx.x & 63;
    int row = lane & 15;
    int kb = lane >> 4;
    int ct0 = wave * 2;

    bf16x8 bh[2][8], bl[2][8];
#pragma unroll
    for (int c = 0; c < 2; ++c)
#pragma unroll
        for (int kc = 0; kc < 8; ++kc) {
            size_t widx = (size_t)((ct0 + c) * 16 + row) * 256 + kc * 32 + kb * 8;
            bh[c][kc] = *(const bf16x8*)(Whi + widx);
            bl[c][kc] = *(const bf16x8*)(Wlo + widx);
        }
    float b0 = bias[ct0 * 16 + row];
    float b1 = bias[ct0 * 16 + 16 + row];

    for (int t = blockIdx.x; t < NTILE; t += gridDim.x) {
        int n0 = t * 16;
        size_t rb = (size_t)(n0 + row) * 128 + kb * 8;
        bf16x8 ah[8], al[8];
#pragma unroll
        for (int kc = 0; kc < 4; ++kc) {
            ah[kc] = *(const bf16x8*)(Ahi0 + rb + kc * 32);
            al[kc] = *(const bf16x8*)(Alo0 + rb + kc * 32);
        }
#pragma unroll
        for (int kc = 0; kc < 4; ++kc) {
            ah[4 + kc] = *(const bf16x8*)(Ahi1 + rb + kc * 32);
            al[4 + kc] = *(const bf16x8*)(Alo1 + rb + kc * 32);
        }
        f32x4 acc0 = {0.f, 0.f, 0.f, 0.f};
        f32x4 acc1 = {0.f, 0.f, 0.f, 0.f};
#pragma unroll
        for (int kc = 0; kc < 8; ++kc) {
            acc0 = __builtin_amdgcn_mfma_f32_16x16x32_bf16(ah[kc], bh[0][kc], acc0, 0, 0, 0);
            acc0 = __builtin_amdgcn_mfma_f32_16x16x32_bf16(al[kc], bh[0][kc], acc0, 0, 0, 0);
            acc0 = __builtin_amdgcn_mfma_f32_16x16x32_bf16(ah[kc], bl[0][kc], acc0, 0, 0, 0);
            acc1 = __builtin_amdgcn_mfma_f32_16x16x32_bf16(ah[kc], bh[1][kc], acc1, 0, 0, 0);
            acc1 = __builtin_amdgcn_mfma_f32_16x16x32_bf16(al[kc], bh[1][kc], acc1, 0, 0, 0);
            acc1 = __builtin_amdgcn_mfma_f32_16x16x32_bf16(ah[kc], bl[1][kc], acc1, 0, 0, 0);
        }
        __syncthreads();   // all waves' reads of this tile's rows precede writes
        int cb0 = ct0 * 16 + row;
#pragma unroll
        for (int r = 0; r < 4; ++r) {
            int n = n0 + kb * 4 + r;         // D: col=lane&15, row=(lane>>4)*4+reg
            size_t ro = (size_t)n * 128;
            unsigned p0 = pack_split(fmaxf(acc0[r] + b0, 0.f));
            unsigned p1 = pack_split(fmaxf(acc1[r] + b1, 0.f));
            Ohi[ro + cb0]      = (unsigned short)(p0 >> 16);
            Olo[ro + cb0]      = (unsigned short)(p0 & 0xFFFFu);
            Ohi[ro + cb0 + 16] = (unsigned short)(p1 >> 16);
            Olo[ro + cb0 + 16] = (unsigned short)(p1 & 0xFFFFu);
        }
    }
}

// layer-2 variant: head fused — out[n] += sum_c relu(h3[n][c]) * Wf[c]
__global__ __launch_bounds__(256, 2) void k_gemm_head(
        const unsigned short* __restrict__ Ahi0, const unsigned short* __restrict__ Alo0,
        const unsigned short* __restrict__ Ahi1, const unsigned short* __restrict__ Alo1,
        const unsigned short* __restrict__ Whi, const unsigned short* __restrict__ Wlo,
        const float* __restrict__ bias, const float* __restrict__ Wf,
        float* __restrict__ out) {
    int wave = __builtin_amdgcn_readfirstlane(threadIdx.x >> 6);
    int lane = threadIdx.x & 63;
    int row = lane & 15;
    int kb = lane >> 4;
    int ct0 = wave * 2;

    bf16x8 bh[2][8], bl[2][8];
#pragma unroll
    for (int c = 0; c < 2; ++c)
#pragma unroll
        for (int kc = 0; kc < 8; ++kc) {
            size_t widx = (size_t)((ct0 + c) * 16 + row) * 256 + kc * 32 + kb * 8;
            bh[c][kc] = *(const bf16x8*)(Whi + widx);
            bl[c][kc] = *(const bf16x8*)(Wlo + widx);
        }
    float b0 = bias[ct0 * 16 + row];
    float b1 = bias[ct0 * 16 + 16 + row];
    float w0 = Wf[ct0 * 16 + row];
    float w1 = Wf[ct0 * 16 + 16 + row];

    for (int t = blockIdx.x; t < NTILE; t += gridDim.x) {
        int n0 = t * 16;
        size_t rb = (size_t)(n0 + row) * 128 + kb * 8;
        bf16x8 ah[8], al[8];
#pragma unroll
        for (int kc = 0; kc < 4; ++kc) {
            ah[kc] = *(const bf16x8*)(Ahi0 + rb + kc * 32);
            al[kc] = *(const bf16x8*)(Alo0 + rb + kc * 32);
        }
#pragma unroll
        for (int kc = 0; kc < 4; ++kc) {
            ah[4 + kc] = *(const bf16x8*)(Ahi1 + rb + kc * 32);
            al[4 + kc] = *(const bf16x8*)(Alo1 + rb + kc * 32);
        }
        f32x4 acc0 = {0.f, 0.f, 0.f, 0.f};
        f32x4 acc1 = {0.f, 0.f, 0.f, 0.f};
#pragma unroll
        for (int kc = 0; kc < 8; ++kc) {
            acc0 = __builtin_amdgcn_mfma_f32_16x16x32_bf16(ah[kc], bh[0][kc], acc0, 0, 0, 0);
            acc0 = __builtin_amdgcn_mfma_f32_16x16x32_bf16(al[kc], bh[0][kc], acc0, 0, 0, 0);
            acc0 = __builtin_amdgcn_mfma_f32_16x16x32_bf16(ah[kc], bl[0][kc], acc0, 0, 0, 0);
            acc1 = __builtin_amdgcn_mfma_f32_16x16x32_bf16(ah[kc], bh[1][kc], acc1, 0, 0, 0);
            acc1 = __builtin_amdgcn_mfma_f32_16x16x32_bf16(al[kc], bh[1][kc], acc1, 0, 0, 0);
            acc1 = __builtin_amdgcn_mfma_f32_16x16x32_bf16(ah[kc], bl[1][kc], acc1, 0, 0, 0);
        }
        float part[4];
#pragma unroll
        for (int r = 0; r < 4; ++r)
            part[r] = fmaxf(acc0[r] + b0, 0.f) * w0 + fmaxf(acc1[r] + b1, 0.f) * w1;
#pragma unroll
        for (int o = 1; o < 16; o <<= 1) {
#pragma unroll
            for (int r = 0; r < 4; ++r) part[r] += __shfl_xor(part[r], o);
        }
        if (row == 0) {
#pragma unroll
            for (int r = 0; r < 4; ++r) atomicAdd(&out[n0 + kb * 4 + r], part[r]);
        }
    }
}

extern "C" void kernel_launch(void* const* d_in, const int* in_sizes, int n_in,
                              void* d_out, int out_size, void* d_ws, size_t ws_size,
                              hipStream_t stream) {
    const float* x   = (const float*)d_in[0];
    const int*   ei  = (const int*)d_in[1];
    const float* Wl0 = (const float*)d_in[2];
    const float* bl0 = (const float*)d_in[3];
    const float* Wr0 = (const float*)d_in[4];
    const float* Wl1 = (const float*)d_in[5];
    const float* bl1 = (const float*)d_in[6];
    const float* Wr1 = (const float*)d_in[7];
    const float* Wl2 = (const float*)d_in[8];
    const float* bl2 = (const float*)d_in[9];
    const float* Wr2 = (const float*)d_in[10];
    const float* Wf  = (const float*)d_in[11];
    const float* bf  = (const float*)d_in[12];
    float* out = (float*)d_out;

    char* p = (char*)d_ws;
    auto alloc = [&](size_t n) { void* r = (void*)p; p += (n + 255) & ~(size_t)255; return r; };
    int*            hist      = (int*)alloc((size_t)NBLK * 256 * 4);
    int*            tot       = (int*)alloc(256 * 4);
    int*            dbase     = (int*)alloc(257 * 4);
    int*            cnt       = (int*)alloc((size_t)NN * 4);
    int*            row_start = (int*)alloc((size_t)NN * 4);
    unsigned short* perm      = (unsigned short*)alloc((size_t)NE * 2);
    unsigned short* s_hi      = (unsigned short*)alloc((size_t)NN * 128 * 2);
    unsigned short* s_lo      = (unsigned short*)alloc((size_t)NN * 128 * 2);
    unsigned short* h_hi      = (unsigned short*)alloc((size_t)NN * 128 * 2);
    unsigned short* h_lo      = (unsigned short*)alloc((size_t)NN * 128 * 2);
    unsigned short* whi       = (unsigned short*)alloc((size_t)3 * 128 * 256 * 2);
    unsigned short* wlo       = (unsigned short*)alloc((size_t)3 * 128 * 256 * 2);
    unsigned*       packed    = (unsigned*)s_hi;  // 3.2MB < 12.8MB; consumed
                                                  // by bucket_csr before agg

    dim3 b256(256);
    // CSR build via bucket sort
    k_hist<<<dim3(NBLK), b256, 0, stream>>>(ei, hist);
    k_colscan<<<dim3(256), b256, 0, stream>>>(hist, tot);
    k_total<<<dim3(1), b256, 0, stream>>>(tot, dbase);
    k_addbase<<<dim3(NBLK), b256, 0, stream>>>(hist, dbase);
    k_scatter1<<<dim3(NBLK), b256, 0, stream>>>(ei, hist, packed);
    k_bucket_csr<<<dim3(NBUCK), b256, 0, stream>>>(packed, dbase, perm, cnt, row_start);

    // packing + out init
    k_pack_x<<<dim3((NN * 128 / 4 + 255) / 256), b256, 0, stream>>>(x, h_hi, h_lo);
    k_pack_w<<<dim3(128), b256, 0, stream>>>(Wl0, Wr0, whi + 0 * 32768, wlo + 0 * 32768);
    k_pack_w<<<dim3(128), b256, 0, stream>>>(Wl1, Wr1, whi + 1 * 32768, wlo + 1 * 32768);
    k_pack_w<<<dim3(128), b256, 0, stream>>>(Wl2, Wr2, whi + 2 * 32768, wlo + 2 * 32768);
    k_init_out<<<dim3((NN + 255) / 256), b256, 0, stream>>>(out, bf);

    dim3 gAgg((NN + 3) / 4);    // 1 node/wave, 4 per block
    dim3 gGemm(512);            // 2 blocks/CU; grid-stride over 3125 tiles

    // layer 0
    k_aggregate<<<gAgg, b256, 0, stream>>>(h_hi, row_start, cnt, perm, s_hi, s_lo);
    k_gemm_ws<<<gGemm, b256, 0, stream>>>(s_hi, s_lo, h_hi, h_lo,
                                          whi + 0 * 32768, wlo + 0 * 32768, bl0, h_hi, h_lo);
    // layer 1 (in place)
    k_aggregate<<<gAgg, b256, 0, stream>>>(h_hi, row_start, cnt, perm, s_hi, s_lo);
    k_gemm_ws<<<gGemm, b256, 0, stream>>>(s_hi, s_lo, h_hi, h_lo,
                                          whi + 1 * 32768, wlo + 1 * 32768, bl1, h_hi, h_lo);
    // layer 2 + fused head
    k_aggregate<<<gAgg, b256, 0, stream>>>(h_hi, row_start, cnt, perm, s_hi, s_lo);
    k_gemm_head<<<gGemm, b256, 0, stream>>>(s_hi, s_lo, h_hi, h_lo,
                                            whi + 2 * 32768, wlo + 2 * 32768, bl2, Wf, out);
}